// Round 3
// baseline (470.801 us; speedup 1.0000x reference)
//
#include <hip/hip_runtime.h>

// EGNN — algebraic collapse:
//   alpha = outer(v,v)/S is rank-1; v = first 32 rows of normalized Ep;
//   S = 8192 exactly. out[i,:] = softmax(v_i/S * (W @ (X^T v)) + b).
// R3 vs R2 (458us):
//  - k_g + k_ep fused (k_gep): g lives in VGPRs, never hits HBM (was 16MB rt).
//  - y = W@u computed ONCE (k_y) instead of per-block in k_out_alpha
//    (kills a 64-line W-gather * 2048 blocks ~ 20us).
//  - k_out_alpha is now: load y -> softmax (2 barriers) -> pure store stream.

#define LEAKY 0.01f
constexpr float INV_S = 1.0f / 8192.0f;

// ---- k_gep: 256 blocks x 256 thr. Block p: m in [32p, 32p+32). ----------
// thread t: c=t&127 -> cols k0=2c,k1=2c+1; h=t>>7 -> local rows [16h,16h+16).
// Phase 1: g[m][k] = exp(lrelu(s*(X@W^T+b))) into registers (16 m x 2 k).
// Phase 2: part[j][2p+h][k] = sum_{m in half} E[j][m]*g[m][k], j<32.
__global__ __launch_bounds__(256) void k_gep(const float* __restrict__ X,
                                             const float* __restrict__ W,
                                             const float* __restrict__ b,
                                             const float* __restrict__ Ai,
                                             const float* __restrict__ Aj,
                                             const float* __restrict__ E,
                                             float* __restrict__ part) {
    __shared__ float4 Xs[32 * 32];   // 32 rows x 128 floats = 16 KB
    __shared__ float4 Es4[32][8];    // 32 j x 32 m = 4 KB
    __shared__ float sred[4];
    int t = threadIdx.x;
    int p = blockIdx.x;
    int m0 = p * 32;

    // s = sum(Ai)+sum(Aj), redundant per block
    float val = (t < 128) ? Ai[t] : Aj[t - 128];
    for (int off = 32; off > 0; off >>= 1) val += __shfl_down(val, off, 64);
    if ((t & 63) == 0) sred[t >> 6] = val;

    // stage X rows m0..m0+31 (1024 float4, 4/thread) and E[0..32)[m0..m0+32)
    const float4* X4 = (const float4*)(X + (size_t)m0 * 128);
    Xs[t] = X4[t];
    Xs[t + 256] = X4[t + 256];
    Xs[t + 512] = X4[t + 512];
    Xs[t + 768] = X4[t + 768];
    {
        int j = t >> 3, q = t & 7;
        Es4[j][q] = *(const float4*)(E + (size_t)j * 8192 + m0 + q * 4);
    }
    __syncthreads();

    float s = sred[0] + sred[1] + sred[2] + sred[3];
    int c = t & 127, h = t >> 7;
    int k0 = 2 * c, k1 = k0 + 1;
    const float4* W0 = (const float4*)(W + (size_t)k0 * 128);
    const float4* W1 = (const float4*)(W + (size_t)k1 * 128);
    float bk0 = b[k0], bk1 = b[k1];

    float g0[16], g1[16];
#pragma unroll
    for (int r = 0; r < 16; r++) { g0[r] = 0.f; g1[r] = 0.f; }

    const float4* Xrow = Xs + (size_t)h * 512;  // 16 rows x 32 float4
#pragma unroll 2
    for (int c4 = 0; c4 < 32; c4++) {
        float4 w0 = W0[c4];
        float4 w1 = W1[c4];
#pragma unroll
        for (int r = 0; r < 16; r++) {
            float4 x = Xrow[r * 32 + c4];  // wave-uniform -> LDS broadcast
            g0[r] += w0.x * x.x + w0.y * x.y + w0.z * x.z + w0.w * x.w;
            g1[r] += w1.x * x.x + w1.y * x.y + w1.z * x.z + w1.w * x.w;
        }
    }
#pragma unroll
    for (int r = 0; r < 16; r++) {
        float a0 = s * (g0[r] + bk0);
        a0 = (a0 >= 0.f) ? a0 : LEAKY * a0;
        g0[r] = expf(a0);
        float a1 = s * (g1[r] + bk1);
        a1 = (a1 >= 0.f) ? a1 : LEAKY * a1;
        g1[r] = expf(a1);
    }

    // E phase: acc over this thread's 16 rows (local m = 16h + 4*r4 + i)
    float a0a[32], a1a[32];
#pragma unroll
    for (int j = 0; j < 32; j++) { a0a[j] = 0.f; a1a[j] = 0.f; }
#pragma unroll
    for (int r4 = 0; r4 < 4; r4++) {
#pragma unroll
        for (int j = 0; j < 32; j++) {
            float4 e = Es4[j][h * 4 + r4];  // wave-uniform broadcast
            a0a[j] += e.x * g0[r4 * 4 + 0] + e.y * g0[r4 * 4 + 1] +
                      e.z * g0[r4 * 4 + 2] + e.w * g0[r4 * 4 + 3];
            a1a[j] += e.x * g1[r4 * 4 + 0] + e.y * g1[r4 * 4 + 1] +
                      e.z * g1[r4 * 4 + 2] + e.w * g1[r4 * 4 + 3];
        }
    }

    int slot = 2 * p + h;  // 0..511
#pragma unroll
    for (int j = 0; j < 32; j++) {
        float2 st = make_float2(a0a[j], a1a[j]);
        *(float2*)(part + ((size_t)j * 512 + slot) * 256 + k0) = st;
    }
}

// ---- k_vu: 32 blocks x 1024 threads. -------------------------------------
// Phase 1: v[j*256+k] = Ep[j,k]/rowsum_j (reduce part over 512 slots).
// Phase 2: upart[j*128+c] = sum_{t<256} v[j*256+t] * X[j*256+t][c].
__global__ __launch_bounds__(1024) void k_vu(const float* __restrict__ part,
                                             const float* __restrict__ X,
                                             float* __restrict__ v,
                                             float* __restrict__ upart) {
    int tid = threadIdx.x;
    int k = tid & 255;
    int q = tid >> 8;  // 0..3
    int j = blockIdx.x;

    const float* base = part + (size_t)j * 512 * 256 + k;
    float a = 0.f;
    for (int sl = q * 128; sl < q * 128 + 128; sl++) a += base[(size_t)sl * 256];
    __shared__ float red[1024];
    __shared__ float v_s[256];
    __shared__ float red4[16];
    red[tid] = a;
    __syncthreads();

    float ep = 0.f;
    if (q == 0) ep = red[k] + red[k + 256] + red[k + 512] + red[k + 768];
    float w = ep;  // q>0 contributes 0
    for (int off = 32; off > 0; off >>= 1) w += __shfl_down(w, off, 64);
    if ((tid & 63) == 0) red4[tid >> 6] = w;
    __syncthreads();
    if (q == 0) {
        float r = red4[0] + red4[1] + red4[2] + red4[3];
        float vk = ep / r;
        v[(size_t)j * 256 + k] = vk;
        v_s[k] = vk;
    }
    __syncthreads();

    // phase 2: 1024 threads = 128 c x 8 groups; group handles 32 rows
    int c = tid & 127;
    int grp = tid >> 7;  // 0..7
    const float* Xp = X + ((size_t)j * 256 + grp * 32) * 128 + c;
    float acc = 0.f;
#pragma unroll 4
    for (int t = 0; t < 32; t++) acc += v_s[grp * 32 + t] * Xp[(size_t)t * 128];
    red[tid] = acc;
    __syncthreads();
    if (tid < 128) {
        float s = 0.f;
#pragma unroll
        for (int gg = 0; gg < 8; gg++) s += red[gg * 128 + tid];
        upart[(size_t)j * 128 + tid] = s;
    }
}

// ---- k_y: y = W @ u, once. 1 block x 256. --------------------------------
__global__ __launch_bounds__(256) void k_y(const float* __restrict__ upart,
                                           const float* __restrict__ W,
                                           float* __restrict__ y) {
    __shared__ float u_s[128];
    int k = threadIdx.x;
    if (k < 128) {
        float a = 0.f;
#pragma unroll
        for (int j = 0; j < 32; j++) a += upart[(size_t)j * 128 + k];
        u_s[k] = a;
    }
    __syncthreads();
    const float4* W4 = (const float4*)(W + (size_t)k * 128);
    const float4* u4 = (const float4*)u_s;
    float acc = 0.f;
#pragma unroll 8
    for (int c4 = 0; c4 < 32; c4++) {
        float4 w = W4[c4];
        float4 uu = u4[c4];
        acc += w.x * uu.x + w.y * uu.y + w.z * uu.z + w.w * uu.w;
    }
    y[k] = acc;
}

// ---- k_out_alpha: softmax-out + alpha write. 2048 blocks x 4 rows. -------
// out[i,:] = softmax(v[i]*INV_S*y + b); alpha[i,:] = (v[i]*INV_S) * v.
// 2 barriers, then one uninterrupted run of 32 float4 regular stores/thread.
__global__ __launch_bounds__(256) void k_out_alpha(const float* __restrict__ v,
                                                   const float* __restrict__ y,
                                                   const float* __restrict__ b,
                                                   float* __restrict__ out,
                                                   float* __restrict__ alpha) {
    __shared__ float redm[4][4];
    __shared__ float reds[4][4];
    int k = threadIdx.x;
    float yk = y[k];
    float bk = b[k];
    const float4* v4 = (const float4*)v;
    float4 vv[8];
#pragma unroll
    for (int jj = 0; jj < 8; jj++) vv[jj] = v4[k + jj * 256];

    int i0 = blockIdx.x * 4;
    float vi[4], e[4];
#pragma unroll
    for (int rr = 0; rr < 4; rr++) {
        vi[rr] = v[i0 + rr] * INV_S;
        float z = vi[rr] * yk + bk;
        float mm = z;
        for (int off = 32; off > 0; off >>= 1) mm = fmaxf(mm, __shfl_down(mm, off, 64));
        if ((k & 63) == 0) redm[rr][k >> 6] = mm;
        e[rr] = z;  // stash z
    }
    __syncthreads();
#pragma unroll
    for (int rr = 0; rr < 4; rr++) {
        float mm = fmaxf(fmaxf(redm[rr][0], redm[rr][1]), fmaxf(redm[rr][2], redm[rr][3]));
        float ee = expf(e[rr] - mm);
        e[rr] = ee;
        float ss = ee;
        for (int off = 32; off > 0; off >>= 1) ss += __shfl_down(ss, off, 64);
        if ((k & 63) == 0) reds[rr][k >> 6] = ss;
    }
    __syncthreads();
#pragma unroll
    for (int rr = 0; rr < 4; rr++) {
        float ss = reds[rr][0] + reds[rr][1] + reds[rr][2] + reds[rr][3];
        out[(size_t)(i0 + rr) * 256 + k] = e[rr] / ss;
    }

    // pure alpha store stream
#pragma unroll
    for (int rr = 0; rr < 4; rr++) {
        float sc = vi[rr];
        float4* A4 = (float4*)(alpha + (size_t)(i0 + rr) * 8192);
#pragma unroll
        for (int jj = 0; jj < 8; jj++) {
            float4 t = vv[jj];
            A4[k + jj * 256] = make_float4(t.x * sc, t.y * sc, t.z * sc, t.w * sc);
        }
    }
}

extern "C" void kernel_launch(void* const* d_in, const int* in_sizes, int n_in,
                              void* d_out, int out_size, void* d_ws, size_t ws_size,
                              hipStream_t stream) {
    const float* X  = (const float*)d_in[0];  // 8192 x 128
    const float* E  = (const float*)d_in[1];  // 8192 x 8192
    const float* W  = (const float*)d_in[2];  // 256 x 128
    const float* b  = (const float*)d_in[3];  // 256
    const float* Ai = (const float*)d_in[4];  // 128
    const float* Aj = (const float*)d_in[5];  // 128

    float* out   = (float*)d_out;             // 8192*256
    float* alpha = out + 2097152;             // 8192*8192

    // part scratch (32*512*256 = 16 MB) lives at the START of the alpha
    // region; consumed by k_vu before k_out_alpha writes alpha (stream order).
    float* part  = alpha;

    float* ws    = (float*)d_ws;
    float* v     = ws;                        // 8192
    float* upart = v + 8192;                  // 32*128 = 4096
    float* y     = upart + 4096;              // 256

    k_gep<<<256, 256, 0, stream>>>(X, W, b, Ai, Aj, E, part);
    k_vu<<<32, 1024, 0, stream>>>(part, X, v, upart);
    k_y<<<1, 256, 0, stream>>>(upart, W, y);
    k_out_alpha<<<2048, 256, 0, stream>>>(v, y, b, out, alpha);
}